// Round 12
// baseline (115.884 us; speedup 1.0000x reference)
//
#include <hip/hip_runtime.h>
#include <hip/hip_bf16.h>
#include <math.h>

#define DIM 256

typedef float f32x4 __attribute__((ext_vector_type(4)));
typedef int   i32x8 __attribute__((ext_vector_type(8)));

__constant__ const float kTempInvLog2e = 20.0f * 1.4426950408889634f; // (1/temp)*log2(e)
#define LN2 0.6931471805599453f
#define EPS_NORM 1e-8f
#define SCALE_ONE 0x7F7F7F7Fu   // e8m0 bias-127 in every byte = x1.0

// f32x4 -> 4 packed OCP e4m3 bytes via HW cvt_pk (2 instrs, RNE-sat)
static __device__ inline unsigned f2fp8x4(float4 v, float s) {
    int r = 0;
    r = __builtin_amdgcn_cvt_pk_fp8_f32(v.x * s, v.y * s, r, false); // low word
    r = __builtin_amdgcn_cvt_pk_fp8_f32(v.z * s, v.w * s, r, true);  // high word
    return (unsigned)r;
}

// assemble a 32-byte (8 VGPR) MFMA operand from two 16-B pieces
static __device__ inline i32x8 ld_frag32(const void* p0, const void* p1) {
    uint4 a = *(const uint4*)p0;
    uint4 b = *(const uint4*)p1;
    i32x8 v;
    v[0] = a.x; v[1] = a.y; v[2] = a.z; v[3] = a.w;
    v[4] = b.x; v[5] = b.y; v[6] = b.z; v[7] = b.w;
    return v;
}

// Kernel 1: normalize + fp8-quantize (HW cvt) + PACK for the K=128 scaled-MFMA
// fragment. 16-row tile T, K-chunk kc (128 k). Chunk CI = T*2+kc is 2048 B:
//   byte = CI*2048 + piece*1024 + lane*16, lane = rowlocal + 16*g,
//   holding X[row][kc*128 + g*32 + piece*16 .. +16].
// Block = 256 thr handles 16 rows of BOTH A and B. Also diag[r] (exact fp32).
__global__ __launch_bounds__(256) void normpack_kernel(
    const float* __restrict__ A, const float* __restrict__ B,
    unsigned char* __restrict__ Apk, unsigned char* __restrict__ Bpk,
    float* __restrict__ diag, int n)
{
    __shared__ uint4 lA[256];
    __shared__ uint4 lB[256];
    const int t = threadIdx.x;
    const int rl = t >> 4;       // row-local 0..15
    const int c16 = t & 15;      // 16-elem chunk: abs k in [16*c16, 16*c16+16)
    const int r = blockIdx.x * 16 + rl;

    const float4* pa = (const float4*)(A + (size_t)r * DIM + c16 * 16);
    const float4* pb = (const float4*)(B + (size_t)r * DIM + c16 * 16);
    float4 a0 = pa[0], a1 = pa[1], a2 = pa[2], a3 = pa[3];
    float4 b0 = pb[0], b1 = pb[1], b2 = pb[2], b3 = pb[3];

    float ssa = a0.x*a0.x + a0.y*a0.y + a0.z*a0.z + a0.w*a0.w
              + a1.x*a1.x + a1.y*a1.y + a1.z*a1.z + a1.w*a1.w
              + a2.x*a2.x + a2.y*a2.y + a2.z*a2.z + a2.w*a2.w
              + a3.x*a3.x + a3.y*a3.y + a3.z*a3.z + a3.w*a3.w;
    float ssb = b0.x*b0.x + b0.y*b0.y + b0.z*b0.z + b0.w*b0.w
              + b1.x*b1.x + b1.y*b1.y + b1.z*b1.z + b1.w*b1.w
              + b2.x*b2.x + b2.y*b2.y + b2.z*b2.z + b2.w*b2.w
              + b3.x*b3.x + b3.y*b3.y + b3.z*b3.z + b3.w*b3.w;
    float dd  = a0.x*b0.x + a0.y*b0.y + a0.z*b0.z + a0.w*b0.w
              + a1.x*b1.x + a1.y*b1.y + a1.z*b1.z + a1.w*b1.w
              + a2.x*b2.x + a2.y*b2.y + a2.z*b2.z + a2.w*b2.w
              + a3.x*b3.x + a3.y*b3.y + a3.z*b3.z + a3.w*b3.w;
#pragma unroll
    for (int m = 1; m < 16; m <<= 1) {
        ssa += __shfl_xor(ssa, m, 64);
        ssb += __shfl_xor(ssb, m, 64);
        dd  += __shfl_xor(dd, m, 64);
    }
    float na = fmaxf(sqrtf(ssa), EPS_NORM);
    float nb = fmaxf(sqrtf(ssb), EPS_NORM);
    float sa = kTempInvLog2e / na;
    float sb = 1.0f / nb;
    if (c16 == 0) diag[r] = dd / (na * nb) * kTempInvLog2e;

    // kc = c16>>3, g = (c16&7)>>1, piece = c16&1, lane = rl + 16*g
    const int u = ((c16 >> 3) << 7) + ((c16 & 1) << 6) + rl + ((c16 & 7) >> 1) * 16;
    uint4 ga, gb;
    ga.x = f2fp8x4(a0, sa); ga.y = f2fp8x4(a1, sa);
    ga.z = f2fp8x4(a2, sa); ga.w = f2fp8x4(a3, sa);
    gb.x = f2fp8x4(b0, sb); gb.y = f2fp8x4(b1, sb);
    gb.z = f2fp8x4(b2, sb); gb.w = f2fp8x4(b3, sb);
    lA[u] = ga; lB[u] = gb;
    __syncthreads();

    ((uint4*)Apk)[(size_t)blockIdx.x * 256 + t] = lA[t];
    ((uint4*)Bpk)[(size_t)blockIdx.x * 256 + t] = lB[t];
}

// async 16B/lane global->LDS copy (wave-uniform LDS base + lane*16)
static __device__ inline void async_copy16(const void* g, void* l) {
    __builtin_amdgcn_global_load_lds(
        (const __attribute__((address_space(1))) unsigned int*)g,
        (__attribute__((address_space(3))) unsigned int*)l, 16, 0, 0);
}

// Kernel 2: fused MX-fp8 GEMM (16x16x128, identity scales) + exp2 + row sums.
// BARRIER-FREE K-LOOP: the block's whole 256-col B slice (64 KB packed fp8)
// is staged into LDS ONCE (16 async copies/thread + one __syncthreads); the
// compute loop is then pure ds_read+MFMA+exp2 with no barriers and no
// prefetch machinery. LDS 64 KB -> 2 blocks/CU (8 waves/CU), waves drift
// freely and co-schedule MFMA vs VALU pipes.
// Block = 256 thr (4 waves), tile = 256 rows x 256 cols. Wave w owns 64 rows:
// afrag[4 m][2 kc] i32x8 pinned (64 VGPRs); per 16-col tile: 8 MFMAs.
// Grid = 32 rowblk x 32 colblk = 1024 (2 rounds at 2 blocks/CU).
// XCD pinning: colblk = ((i&7)<<2)|((i>>3)&3) -> 256 KB B per XCD L2.
__global__ __launch_bounds__(256, 2) void gemm_lse_kernel(
    const unsigned char* __restrict__ Apk, const unsigned char* __restrict__ Bpk,
    float* __restrict__ partial, int n)
{
    __shared__ char ldsbuf[65536];   // whole 256-col B slice, packed
    const int lane = threadIdx.x & 63;
    const int w = threadIdx.x >> 6;
    const int c = lane & 15;
    const int q = lane >> 4;

    const int i = blockIdx.x;
    const int colblk = ((i & 7) << 2) | ((i >> 3) & 3);  // 0..31, XCD-pinned
    const int rowblk = i >> 5;                            // 0..31
    const int rowbase = rowblk * 256 + w * 64;

    // stage the entire B slice (64 KB) into LDS: wave w copies its 16 KB
    {
        const char* src = (const char*)Bpk + (size_t)colblk * 65536 + w * 16384 + (size_t)lane * 16;
        char* dst = ldsbuf + w * 16384;
#pragma unroll
        for (int j = 0; j < 16; ++j)
            async_copy16(src + j * 1024, dst + j * 1024);
    }

    // A fragments while staging is in flight: 4 row-tiles x 2 K-chunks
    i32x8 afrag[4][2];
#pragma unroll
    for (int m = 0; m < 4; ++m) {
        const int AT = rowblk * 16 + w * 4 + m;
#pragma unroll
        for (int kc = 0; kc < 2; ++kc) {
            const char* base = (const char*)Apk + ((size_t)AT * 2 + kc) * 2048 + lane * 16;
            afrag[m][kc] = ld_frag32(base, base + 1024);
        }
    }
#pragma unroll
    for (int m = 0; m < 4; ++m)
#pragma unroll
        for (int kc = 0; kc < 2; ++kc)
            asm volatile("" : "+v"(afrag[m][kc]));  // keep resident

    float sums[16];
#pragma unroll
    for (int s = 0; s < 16; ++s) sums[s] = 0.0f;

    __syncthreads();   // staging complete; ONLY barrier in the kernel

    const char* lb = ldsbuf + (size_t)lane * 16;
#pragma unroll 4
    for (int nc = 0; nc < 16; ++nc) {
        f32x4 acc[4];
#pragma unroll
        for (int m = 0; m < 4; ++m) acc[m] = (f32x4){0.f, 0.f, 0.f, 0.f};
#pragma unroll
        for (int kc = 0; kc < 2; ++kc) {
            const char* p = lb + nc * 4096 + kc * 2048;
            i32x8 bfrag = ld_frag32(p, p + 1024);
#pragma unroll
            for (int m = 0; m < 4; ++m)
                acc[m] = __builtin_amdgcn_mfma_scale_f32_16x16x128_f8f6f4(
                    afrag[m][kc], bfrag, acc[m],
                    0, 0,                       // cbsz=fp8(e4m3), blgp=fp8(e4m3)
                    0, SCALE_ONE,               // opsel_a, scale_a (x1.0)
                    0, SCALE_ONE);              // opsel_b, scale_b (x1.0)
        }
#pragma unroll
        for (int m = 0; m < 4; ++m)
#pragma unroll
            for (int r = 0; r < 4; ++r)
                sums[m * 4 + r] += __builtin_amdgcn_exp2f(acc[m][r]);
    }

    // reduce row sums across the 16 lanes of each q-group (cols mod 16)
#pragma unroll
    for (int s = 0; s < 16; ++s) {
        float v = sums[s];
        v += __shfl_xor(v, 1, 64);
        v += __shfl_xor(v, 2, 64);
        v += __shfl_xor(v, 4, 64);
        v += __shfl_xor(v, 8, 64);
        sums[s] = v;
    }
    if (c == 0) {
#pragma unroll
        for (int m = 0; m < 4; ++m)
#pragma unroll
            for (int r = 0; r < 4; ++r)
                partial[(size_t)(rowbase + m * 16 + q * 4 + r) * 32 + colblk] = sums[m * 4 + r];
    }
}

// Kernel 3: single-block finale. 1024 thr, 8 rows/thread:
// loss = (ln2/n) * sum_rows( log2(sum_colblks partial) - diag[row] )
__global__ __launch_bounds__(1024) void finale_kernel(
    const float* __restrict__ partial, const float* __restrict__ diag,
    float* __restrict__ out, int n)
{
    __shared__ float red[1024];
    float local = 0.0f;
    for (int row = threadIdx.x; row < n; row += 1024) {
        const float4* p = (const float4*)(partial + (size_t)row * 32);
        float s = 0.0f;
#pragma unroll
        for (int j = 0; j < 8; ++j) {
            float4 v = p[j];
            s += (v.x + v.y) + (v.z + v.w);
        }
        local += log2f(s) - diag[row];
    }
    red[threadIdx.x] = local;
    __syncthreads();
    for (int off = 512; off > 0; off >>= 1) {
        if (threadIdx.x < off) red[threadIdx.x] += red[threadIdx.x + off];
        __syncthreads();
    }
    if (threadIdx.x == 0) out[0] = red[0] * (LN2 / (float)n);
}

extern "C" void kernel_launch(void* const* d_in, const int* in_sizes, int n_in,
                              void* d_out, int out_size, void* d_ws, size_t ws_size,
                              hipStream_t stream) {
    const int n = in_sizes[0] / DIM;  // 8192
    const float* A = (const float*)d_in[0];
    const float* B = (const float*)d_in[1];
    float* out = (float*)d_out;

    // workspace layout
    unsigned char* Apk = (unsigned char*)d_ws;                   // n*DIM fp8 (2 MB)
    unsigned char* Bpk = Apk + (size_t)n * DIM;                  // n*DIM fp8 (2 MB)
    float* partial = (float*)(Bpk + (size_t)n * DIM);            // n*32 f32 (1 MB)
    float* diag = partial + (size_t)n * 32;                      // n f32

    normpack_kernel<<<n / 16, 256, 0, stream>>>(A, B, Apk, Bpk, diag, n);

    // 32 rowblk x 32 colblk, XCD-decoded in-kernel, LDS-resident B slice
    gemm_lse_kernel<<<(n / 256) * 32, 256, 0, stream>>>(Apk, Bpk, partial, n);

    finale_kernel<<<1, 1024, 0, stream>>>(partial, diag, out, n);
}

// Round 13
// 97.245 us; speedup vs baseline: 1.1917x; 1.1917x over previous
//
#include <hip/hip_runtime.h>
#include <hip/hip_bf16.h>
#include <math.h>

#define DIM 256

typedef float f32x4 __attribute__((ext_vector_type(4)));
typedef int   i32x8 __attribute__((ext_vector_type(8)));

__constant__ const float kTempInvLog2e = 20.0f * 1.4426950408889634f; // (1/temp)*log2(e)
#define LN2 0.6931471805599453f
#define EPS_NORM 1e-8f
#define SCALE_ONE 0x7F7F7F7Fu   // e8m0 bias-127 in every byte = x1.0

// f32x4 -> 4 packed OCP e4m3 bytes via HW cvt_pk (2 instrs, RNE-sat)
static __device__ inline unsigned f2fp8x4(float4 v, float s) {
    int r = 0;
    r = __builtin_amdgcn_cvt_pk_fp8_f32(v.x * s, v.y * s, r, false); // low word
    r = __builtin_amdgcn_cvt_pk_fp8_f32(v.z * s, v.w * s, r, true);  // high word
    return (unsigned)r;
}

// assemble a 32-byte (8 VGPR) MFMA operand from two 16-B pieces
static __device__ inline i32x8 ld_frag32(const void* p0, const void* p1) {
    uint4 a = *(const uint4*)p0;
    uint4 b = *(const uint4*)p1;
    i32x8 v;
    v[0] = a.x; v[1] = a.y; v[2] = a.z; v[3] = a.w;
    v[4] = b.x; v[5] = b.y; v[6] = b.z; v[7] = b.w;
    return v;
}

// Kernel 1: normalize + fp8-quantize (HW cvt) + PACK for the K=128 scaled-MFMA
// fragment. 16-row tile T, K-chunk kc (128 k). Chunk CI = T*2+kc is 2048 B:
//   byte = CI*2048 + piece*1024 + lane*16, lane = rowlocal + 16*g,
//   holding X[row][kc*128 + g*32 + piece*16 .. +16].
// Block = 256 thr handles 16 rows of BOTH A and B. Also diag[r] (exact fp32).
__global__ __launch_bounds__(256) void normpack_kernel(
    const float* __restrict__ A, const float* __restrict__ B,
    unsigned char* __restrict__ Apk, unsigned char* __restrict__ Bpk,
    float* __restrict__ diag, int n)
{
    __shared__ uint4 lA[256];
    __shared__ uint4 lB[256];
    const int t = threadIdx.x;
    const int rl = t >> 4;       // row-local 0..15
    const int c16 = t & 15;      // 16-elem chunk: abs k in [16*c16, 16*c16+16)
    const int r = blockIdx.x * 16 + rl;

    const float4* pa = (const float4*)(A + (size_t)r * DIM + c16 * 16);
    const float4* pb = (const float4*)(B + (size_t)r * DIM + c16 * 16);
    float4 a0 = pa[0], a1 = pa[1], a2 = pa[2], a3 = pa[3];
    float4 b0 = pb[0], b1 = pb[1], b2 = pb[2], b3 = pb[3];

    float ssa = a0.x*a0.x + a0.y*a0.y + a0.z*a0.z + a0.w*a0.w
              + a1.x*a1.x + a1.y*a1.y + a1.z*a1.z + a1.w*a1.w
              + a2.x*a2.x + a2.y*a2.y + a2.z*a2.z + a2.w*a2.w
              + a3.x*a3.x + a3.y*a3.y + a3.z*a3.z + a3.w*a3.w;
    float ssb = b0.x*b0.x + b0.y*b0.y + b0.z*b0.z + b0.w*b0.w
              + b1.x*b1.x + b1.y*b1.y + b1.z*b1.z + b1.w*b1.w
              + b2.x*b2.x + b2.y*b2.y + b2.z*b2.z + b2.w*b2.w
              + b3.x*b3.x + b3.y*b3.y + b3.z*b3.z + b3.w*b3.w;
    float dd  = a0.x*b0.x + a0.y*b0.y + a0.z*b0.z + a0.w*b0.w
              + a1.x*b1.x + a1.y*b1.y + a1.z*b1.z + a1.w*b1.w
              + a2.x*b2.x + a2.y*b2.y + a2.z*b2.z + a2.w*b2.w
              + a3.x*b3.x + a3.y*b3.y + a3.z*b3.z + a3.w*b3.w;
#pragma unroll
    for (int m = 1; m < 16; m <<= 1) {
        ssa += __shfl_xor(ssa, m, 64);
        ssb += __shfl_xor(ssb, m, 64);
        dd  += __shfl_xor(dd, m, 64);
    }
    float na = fmaxf(sqrtf(ssa), EPS_NORM);
    float nb = fmaxf(sqrtf(ssb), EPS_NORM);
    float sa = kTempInvLog2e / na;
    float sb = 1.0f / nb;
    if (c16 == 0) diag[r] = dd / (na * nb) * kTempInvLog2e;

    // kc = c16>>3, g = (c16&7)>>1, piece = c16&1, lane = rl + 16*g
    const int u = ((c16 >> 3) << 7) + ((c16 & 1) << 6) + rl + ((c16 & 7) >> 1) * 16;
    uint4 ga, gb;
    ga.x = f2fp8x4(a0, sa); ga.y = f2fp8x4(a1, sa);
    ga.z = f2fp8x4(a2, sa); ga.w = f2fp8x4(a3, sa);
    gb.x = f2fp8x4(b0, sb); gb.y = f2fp8x4(b1, sb);
    gb.z = f2fp8x4(b2, sb); gb.w = f2fp8x4(b3, sb);
    lA[u] = ga; lB[u] = gb;
    __syncthreads();

    ((uint4*)Apk)[(size_t)blockIdx.x * 256 + t] = lA[t];
    ((uint4*)Bpk)[(size_t)blockIdx.x * 256 + t] = lB[t];
}

// async 16B/lane global->LDS copy (wave-uniform LDS base + lane*16)
static __device__ inline void async_copy16(const void* g, void* l) {
    __builtin_amdgcn_global_load_lds(
        (const __attribute__((address_space(1))) unsigned int*)g,
        (__attribute__((address_space(3))) unsigned int*)l, 16, 0, 0);
}

// Kernel 2 (R9 config — the measured optimum): fused MX-fp8 GEMM (16x16x128,
// identity scales) + exp2 + per-row partial sums.
// Block = 256 thr (4 waves). Block tile = 256 rows x 512 cols (1 of 16 splits).
// Wave w owns 64 rows: afrag[4 m][2 kc] i32x8 pinned (64 VGPRs). B streamed as
// 32-col tiles (8 KB packed) through a 2x8 KB LDS double buffer via async
// global_load_lds; each wave reads the whole tile (ds_read_b128, stride-16,
// conflict-free) and feeds each B fragment to 4 MFMAs.
// Grid = 32 rowblocks x 16 splits = 512 blocks (2/CU). XCD-pinned splits:
// split = ((i&7)<<1)|((i>>3)&1) -> 128 KB B-slice per XCD (L2-resident).
__global__ __launch_bounds__(256, 2) void gemm_lse_kernel(
    const unsigned char* __restrict__ Apk, const unsigned char* __restrict__ Bpk,
    float* __restrict__ partial, int n)
{
    __shared__ char ldsbuf[16384];   // 2 x 8 KB B-tile double buffer
    const int lane = threadIdx.x & 63;
    const int w = threadIdx.x >> 6;
    const int c = lane & 15;
    const int q = lane >> 4;

    const int i = blockIdx.x;
    const int split = ((i & 7) << 1) | ((i >> 3) & 1);  // 0..15, XCD-pinned
    const int rowblk = i >> 4;                           // 0..31
    const int rowbase = rowblk * 256 + w * 64;

    // A fragments: 4 row-tiles x 2 K-chunks, 32 B/lane each (two 16-B pieces)
    i32x8 afrag[4][2];
#pragma unroll
    for (int m = 0; m < 4; ++m) {
        const int AT = rowblk * 16 + w * 4 + m;
#pragma unroll
        for (int kc = 0; kc < 2; ++kc) {
            const char* base = (const char*)Apk + ((size_t)AT * 2 + kc) * 2048 + lane * 16;
            afrag[m][kc] = ld_frag32(base, base + 1024);
        }
    }
#pragma unroll
    for (int m = 0; m < 4; ++m)
#pragma unroll
        for (int kc = 0; kc < 2; ++kc)
            asm volatile("" : "+v"(afrag[m][kc]));  // keep resident

    float sums[16];
#pragma unroll
    for (int s = 0; s < 16; ++s) sums[s] = 0.0f;

    const char* bbase = (const char*)Bpk + (size_t)split * 32 * 4096; // 128 KB slice
    const int niter = 16;   // 16 iters of 32 cols

    // stage tile 0 into buffer 0 (each wave copies its 2 KB quarter)
    {
        const char* src = bbase + w * 2048 + (size_t)lane * 16;
        char* dst = ldsbuf + w * 2048;
        async_copy16(src, dst);
        async_copy16(src + 1024, dst + 1024);
    }
    __syncthreads();

    for (int it = 0; it < niter; ++it) {
        const int cur = it & 1;
        if (it + 1 < niter) {   // async prefetch next 8 KB tile
            const char* src = bbase + (size_t)(it + 1) * 8192 + w * 2048 + (size_t)lane * 16;
            char* dst = ldsbuf + (cur ^ 1) * 8192 + w * 2048;
            async_copy16(src, dst);
            async_copy16(src + 1024, dst + 1024);
        }

        f32x4 acc[4][2];
#pragma unroll
        for (int m = 0; m < 4; ++m)
#pragma unroll
            for (int nc = 0; nc < 2; ++nc)
                acc[m][nc] = (f32x4){0.f, 0.f, 0.f, 0.f};

        const char* lb = ldsbuf + cur * 8192 + (size_t)lane * 16;
#pragma unroll
        for (int nc = 0; nc < 2; ++nc) {
#pragma unroll
            for (int kc = 0; kc < 2; ++kc) {
                const char* p = lb + nc * 4096 + kc * 2048;
                i32x8 bfrag = ld_frag32(p, p + 1024);
#pragma unroll
                for (int m = 0; m < 4; ++m)
                    acc[m][nc] = __builtin_amdgcn_mfma_scale_f32_16x16x128_f8f6f4(
                        afrag[m][kc], bfrag, acc[m][nc],
                        0, 0,                       // cbsz=fp8(e4m3), blgp=fp8(e4m3)
                        0, SCALE_ONE,               // opsel_a, scale_a (x1.0)
                        0, SCALE_ONE);              // opsel_b, scale_b (x1.0)
            }
        }

#pragma unroll
        for (int m = 0; m < 4; ++m)
#pragma unroll
            for (int nc = 0; nc < 2; ++nc)
#pragma unroll
                for (int r = 0; r < 4; ++r)
                    sums[m * 4 + r] += __builtin_amdgcn_exp2f(acc[m][nc][r]);

        __syncthreads();   // staging of it+1 complete; all waves done with cur
    }

    // reduce row sums across the 16 lanes of each q-group (cols mod 16)
#pragma unroll
    for (int s = 0; s < 16; ++s) {
        float v = sums[s];
        v += __shfl_xor(v, 1, 64);
        v += __shfl_xor(v, 2, 64);
        v += __shfl_xor(v, 4, 64);
        v += __shfl_xor(v, 8, 64);
        sums[s] = v;
    }
    if (c == 0) {
#pragma unroll
        for (int m = 0; m < 4; ++m)
#pragma unroll
            for (int r = 0; r < 4; ++r)
                partial[(size_t)(rowbase + m * 16 + q * 4 + r) * 16 + split] = sums[m * 4 + r];
    }
}

// Kernel 3: single-block finale. 1024 thr, 8 rows/thread:
// loss = (ln2/n) * sum_rows( log2(sum_splits partial) - diag[row] )
__global__ __launch_bounds__(1024) void finale_kernel(
    const float* __restrict__ partial, const float* __restrict__ diag,
    float* __restrict__ out, int n)
{
    __shared__ float red[1024];
    float local = 0.0f;
    for (int row = threadIdx.x; row < n; row += 1024) {
        const float4* p = (const float4*)(partial + (size_t)row * 16);
        float4 p0 = p[0], p1 = p[1], p2 = p[2], p3 = p[3];
        float s = (p0.x + p0.y + p0.z + p0.w) + (p1.x + p1.y + p1.z + p1.w)
                + (p2.x + p2.y + p2.z + p2.w) + (p3.x + p3.y + p3.z + p3.w);
        local += log2f(s) - diag[row];
    }
    red[threadIdx.x] = local;
    __syncthreads();
    for (int off = 512; off > 0; off >>= 1) {
        if (threadIdx.x < off) red[threadIdx.x] += red[threadIdx.x + off];
        __syncthreads();
    }
    if (threadIdx.x == 0) out[0] = red[0] * (LN2 / (float)n);
}

extern "C" void kernel_launch(void* const* d_in, const int* in_sizes, int n_in,
                              void* d_out, int out_size, void* d_ws, size_t ws_size,
                              hipStream_t stream) {
    const int n = in_sizes[0] / DIM;  // 8192
    const float* A = (const float*)d_in[0];
    const float* B = (const float*)d_in[1];
    float* out = (float*)d_out;

    // workspace layout
    unsigned char* Apk = (unsigned char*)d_ws;                   // n*DIM fp8 (2 MB)
    unsigned char* Bpk = Apk + (size_t)n * DIM;                  // n*DIM fp8 (2 MB)
    float* partial = (float*)(Bpk + (size_t)n * DIM);            // n*16 f32 (512 KB)
    float* diag = partial + (size_t)n * 16;                      // n f32

    normpack_kernel<<<n / 16, 256, 0, stream>>>(A, B, Apk, Bpk, diag, n);

    // 32 rowblocks x 16 splits, XCD-decoded in-kernel, 2 blocks/CU
    gemm_lse_kernel<<<(n / 256) * 16, 256, 0, stream>>>(Apk, Bpk, partial, n);

    finale_kernel<<<1, 1024, 0, stream>>>(partial, diag, out, n);
}

// Round 14
// 90.358 us; speedup vs baseline: 1.2825x; 1.0762x over previous
//
#include <hip/hip_runtime.h>
#include <hip/hip_bf16.h>
#include <math.h>

#define DIM 256

typedef float f32x4 __attribute__((ext_vector_type(4)));
typedef int   i32x8 __attribute__((ext_vector_type(8)));

__constant__ const float kTempInvLog2e = 20.0f * 1.4426950408889634f; // (1/temp)*log2(e)
#define LN2 0.6931471805599453f
#define EPS_NORM 1e-8f
#define SCALE_ONE 0x7F7F7F7Fu   // e8m0 bias-127 in every byte = x1.0

// f32x4 -> 4 packed OCP e4m3 bytes via HW cvt_pk (2 instrs, RNE-sat)
static __device__ inline unsigned f2fp8x4(float4 v, float s) {
    int r = 0;
    r = __builtin_amdgcn_cvt_pk_fp8_f32(v.x * s, v.y * s, r, false); // low word
    r = __builtin_amdgcn_cvt_pk_fp8_f32(v.z * s, v.w * s, r, true);  // high word
    return (unsigned)r;
}

// assemble a 32-byte (8 VGPR) MFMA operand from two 16-B pieces
static __device__ inline i32x8 ld_frag32(const void* p0, const void* p1) {
    uint4 a = *(const uint4*)p0;
    uint4 b = *(const uint4*)p1;
    i32x8 v;
    v[0] = a.x; v[1] = a.y; v[2] = a.z; v[3] = a.w;
    v[4] = b.x; v[5] = b.y; v[6] = b.z; v[7] = b.w;
    return v;
}

// Kernel 1: normalize + fp8-quantize (HW cvt) + PACK for the K=128 scaled-MFMA
// fragment. 16-row tile T, K-chunk kc (128 k). Chunk CI = T*2+kc is 2048 B:
//   byte = CI*2048 + piece*1024 + lane*16, lane = rowlocal + 16*g,
//   holding X[row][kc*128 + g*32 + piece*16 .. +16].
// Block = 256 thr handles 16 rows of BOTH A and B. Also diag[r] (exact fp32).
__global__ __launch_bounds__(256) void normpack_kernel(
    const float* __restrict__ A, const float* __restrict__ B,
    unsigned char* __restrict__ Apk, unsigned char* __restrict__ Bpk,
    float* __restrict__ diag, int n)
{
    __shared__ uint4 lA[256];
    __shared__ uint4 lB[256];
    const int t = threadIdx.x;
    const int rl = t >> 4;       // row-local 0..15
    const int c16 = t & 15;      // 16-elem chunk: abs k in [16*c16, 16*c16+16)
    const int r = blockIdx.x * 16 + rl;

    const float4* pa = (const float4*)(A + (size_t)r * DIM + c16 * 16);
    const float4* pb = (const float4*)(B + (size_t)r * DIM + c16 * 16);
    float4 a0 = pa[0], a1 = pa[1], a2 = pa[2], a3 = pa[3];
    float4 b0 = pb[0], b1 = pb[1], b2 = pb[2], b3 = pb[3];

    float ssa = a0.x*a0.x + a0.y*a0.y + a0.z*a0.z + a0.w*a0.w
              + a1.x*a1.x + a1.y*a1.y + a1.z*a1.z + a1.w*a1.w
              + a2.x*a2.x + a2.y*a2.y + a2.z*a2.z + a2.w*a2.w
              + a3.x*a3.x + a3.y*a3.y + a3.z*a3.z + a3.w*a3.w;
    float ssb = b0.x*b0.x + b0.y*b0.y + b0.z*b0.z + b0.w*b0.w
              + b1.x*b1.x + b1.y*b1.y + b1.z*b1.z + b1.w*b1.w
              + b2.x*b2.x + b2.y*b2.y + b2.z*b2.z + b2.w*b2.w
              + b3.x*b3.x + b3.y*b3.y + b3.z*b3.z + b3.w*b3.w;
    float dd  = a0.x*b0.x + a0.y*b0.y + a0.z*b0.z + a0.w*b0.w
              + a1.x*b1.x + a1.y*b1.y + a1.z*b1.z + a1.w*b1.w
              + a2.x*b2.x + a2.y*b2.y + a2.z*b2.z + a2.w*b2.w
              + a3.x*b3.x + a3.y*b3.y + a3.z*b3.z + a3.w*b3.w;
#pragma unroll
    for (int m = 1; m < 16; m <<= 1) {
        ssa += __shfl_xor(ssa, m, 64);
        ssb += __shfl_xor(ssb, m, 64);
        dd  += __shfl_xor(dd, m, 64);
    }
    float na = fmaxf(sqrtf(ssa), EPS_NORM);
    float nb = fmaxf(sqrtf(ssb), EPS_NORM);
    float sa = kTempInvLog2e / na;
    float sb = 1.0f / nb;
    if (c16 == 0) diag[r] = dd / (na * nb) * kTempInvLog2e;

    // kc = c16>>3, g = (c16&7)>>1, piece = c16&1, lane = rl + 16*g
    const int u = ((c16 >> 3) << 7) + ((c16 & 1) << 6) + rl + ((c16 & 7) >> 1) * 16;
    uint4 ga, gb;
    ga.x = f2fp8x4(a0, sa); ga.y = f2fp8x4(a1, sa);
    ga.z = f2fp8x4(a2, sa); ga.w = f2fp8x4(a3, sa);
    gb.x = f2fp8x4(b0, sb); gb.y = f2fp8x4(b1, sb);
    gb.z = f2fp8x4(b2, sb); gb.w = f2fp8x4(b3, sb);
    lA[u] = ga; lB[u] = gb;
    __syncthreads();

    ((uint4*)Apk)[(size_t)blockIdx.x * 256 + t] = lA[t];
    ((uint4*)Bpk)[(size_t)blockIdx.x * 256 + t] = lB[t];
}

// async 16B/lane global->LDS copy (wave-uniform LDS base + lane*16)
static __device__ inline void async_copy16(const void* g, void* l) {
    __builtin_amdgcn_global_load_lds(
        (const __attribute__((address_space(1))) unsigned int*)g,
        (__attribute__((address_space(3))) unsigned int*)l, 16, 0, 0);
}

// Kernel 2 (R9 config — the measured optimum): fused MX-fp8 GEMM (16x16x128,
// identity scales) + exp2 + per-row partial sums.
// Block = 256 thr (4 waves). Block tile = 256 rows x 512 cols (1 of 16 splits).
// Wave w owns 64 rows: afrag[4 m][2 kc] i32x8 pinned (64 VGPRs). B streamed as
// 32-col tiles (8 KB packed) through a 2x8 KB LDS double buffer via async
// global_load_lds; each wave reads the whole tile (ds_read_b128, stride-16,
// conflict-free) and feeds each B fragment to 4 MFMAs.
// Grid = 32 rowblocks x 16 splits = 512 blocks (2/CU). XCD-pinned splits:
// split = ((i&7)<<1)|((i>>3)&1) -> 128 KB B-slice per XCD (L2-resident).
__global__ __launch_bounds__(256, 2) void gemm_lse_kernel(
    const unsigned char* __restrict__ Apk, const unsigned char* __restrict__ Bpk,
    float* __restrict__ partial, int n)
{
    __shared__ char ldsbuf[16384];   // 2 x 8 KB B-tile double buffer
    const int lane = threadIdx.x & 63;
    const int w = threadIdx.x >> 6;
    const int c = lane & 15;
    const int q = lane >> 4;

    const int i = blockIdx.x;
    const int split = ((i & 7) << 1) | ((i >> 3) & 1);  // 0..15, XCD-pinned
    const int rowblk = i >> 4;                           // 0..31
    const int rowbase = rowblk * 256 + w * 64;

    // A fragments: 4 row-tiles x 2 K-chunks, 32 B/lane each (two 16-B pieces)
    i32x8 afrag[4][2];
#pragma unroll
    for (int m = 0; m < 4; ++m) {
        const int AT = rowblk * 16 + w * 4 + m;
#pragma unroll
        for (int kc = 0; kc < 2; ++kc) {
            const char* base = (const char*)Apk + ((size_t)AT * 2 + kc) * 2048 + lane * 16;
            afrag[m][kc] = ld_frag32(base, base + 1024);
        }
    }
#pragma unroll
    for (int m = 0; m < 4; ++m)
#pragma unroll
        for (int kc = 0; kc < 2; ++kc)
            asm volatile("" : "+v"(afrag[m][kc]));  // keep resident

    float sums[16];
#pragma unroll
    for (int s = 0; s < 16; ++s) sums[s] = 0.0f;

    const char* bbase = (const char*)Bpk + (size_t)split * 32 * 4096; // 128 KB slice
    const int niter = 16;   // 16 iters of 32 cols

    // stage tile 0 into buffer 0 (each wave copies its 2 KB quarter)
    {
        const char* src = bbase + w * 2048 + (size_t)lane * 16;
        char* dst = ldsbuf + w * 2048;
        async_copy16(src, dst);
        async_copy16(src + 1024, dst + 1024);
    }
    __syncthreads();

    for (int it = 0; it < niter; ++it) {
        const int cur = it & 1;
        if (it + 1 < niter) {   // async prefetch next 8 KB tile
            const char* src = bbase + (size_t)(it + 1) * 8192 + w * 2048 + (size_t)lane * 16;
            char* dst = ldsbuf + (cur ^ 1) * 8192 + w * 2048;
            async_copy16(src, dst);
            async_copy16(src + 1024, dst + 1024);
        }

        f32x4 acc[4][2];
#pragma unroll
        for (int m = 0; m < 4; ++m)
#pragma unroll
            for (int nc = 0; nc < 2; ++nc)
                acc[m][nc] = (f32x4){0.f, 0.f, 0.f, 0.f};

        const char* lb = ldsbuf + cur * 8192 + (size_t)lane * 16;
#pragma unroll
        for (int nc = 0; nc < 2; ++nc) {
#pragma unroll
            for (int kc = 0; kc < 2; ++kc) {
                const char* p = lb + nc * 4096 + kc * 2048;
                i32x8 bfrag = ld_frag32(p, p + 1024);
#pragma unroll
                for (int m = 0; m < 4; ++m)
                    acc[m][nc] = __builtin_amdgcn_mfma_scale_f32_16x16x128_f8f6f4(
                        afrag[m][kc], bfrag, acc[m][nc],
                        0, 0,                       // cbsz=fp8(e4m3), blgp=fp8(e4m3)
                        0, SCALE_ONE,               // opsel_a, scale_a (x1.0)
                        0, SCALE_ONE);              // opsel_b, scale_b (x1.0)
            }
        }

#pragma unroll
        for (int m = 0; m < 4; ++m)
#pragma unroll
            for (int nc = 0; nc < 2; ++nc)
#pragma unroll
                for (int r = 0; r < 4; ++r)
                    sums[m * 4 + r] += __builtin_amdgcn_exp2f(acc[m][nc][r]);

        __syncthreads();   // staging of it+1 complete; all waves done with cur
    }

    // reduce row sums across the 16 lanes of each q-group (cols mod 16)
#pragma unroll
    for (int s = 0; s < 16; ++s) {
        float v = sums[s];
        v += __shfl_xor(v, 1, 64);
        v += __shfl_xor(v, 2, 64);
        v += __shfl_xor(v, 4, 64);
        v += __shfl_xor(v, 8, 64);
        sums[s] = v;
    }
    if (c == 0) {
#pragma unroll
        for (int m = 0; m < 4; ++m)
#pragma unroll
            for (int r = 0; r < 4; ++r)
                partial[(size_t)(rowbase + m * 16 + q * 4 + r) * 16 + split] = sums[m * 4 + r];
    }
}

// Kernel 3a: per-row lse - diag, block-reduced. One row per thread, 32 blocks
// (spreads the 544 KB partial read over 32 CUs — the single-block finale was
// serialized on one CU's ~6-10 us read).
__global__ __launch_bounds__(256) void row_lse_kernel(
    const float* __restrict__ partial, const float* __restrict__ diag,
    float* __restrict__ bsum, int n)
{
    __shared__ float red[256];
    const int row = blockIdx.x * 256 + threadIdx.x;
    float local = 0.0f;
    if (row < n) {
        const float4* p = (const float4*)(partial + (size_t)row * 16);
        float4 p0 = p[0], p1 = p[1], p2 = p[2], p3 = p[3];
        float s = (p0.x + p0.y + p0.z + p0.w) + (p1.x + p1.y + p1.z + p1.w)
                + (p2.x + p2.y + p2.z + p2.w) + (p3.x + p3.y + p3.z + p3.w);
        local = log2f(s) - diag[row];
    }
    red[threadIdx.x] = local;
    __syncthreads();
    for (int off = 128; off > 0; off >>= 1) {
        if (threadIdx.x < off) red[threadIdx.x] += red[threadIdx.x + off];
        __syncthreads();
    }
    if (threadIdx.x == 0) bsum[blockIdx.x] = red[0];
}

// Kernel 3b: final reduce of block sums -> loss.
__global__ __launch_bounds__(64) void final_kernel(
    const float* __restrict__ bsum, float* __restrict__ out, int nblocks, int n)
{
    float v = (threadIdx.x < nblocks) ? bsum[threadIdx.x] : 0.0f;
#pragma unroll
    for (int m = 1; m < 64; m <<= 1) v += __shfl_xor(v, m, 64);
    if (threadIdx.x == 0) out[0] = v * (LN2 / (float)n);
}

extern "C" void kernel_launch(void* const* d_in, const int* in_sizes, int n_in,
                              void* d_out, int out_size, void* d_ws, size_t ws_size,
                              hipStream_t stream) {
    const int n = in_sizes[0] / DIM;  // 8192
    const float* A = (const float*)d_in[0];
    const float* B = (const float*)d_in[1];
    float* out = (float*)d_out;

    // workspace layout
    unsigned char* Apk = (unsigned char*)d_ws;                   // n*DIM fp8 (2 MB)
    unsigned char* Bpk = Apk + (size_t)n * DIM;                  // n*DIM fp8 (2 MB)
    float* partial = (float*)(Bpk + (size_t)n * DIM);            // n*16 f32 (512 KB)
    float* diag = partial + (size_t)n * 16;                      // n f32
    float* bsum = diag + n;                                      // 32 f32

    normpack_kernel<<<n / 16, 256, 0, stream>>>(A, B, Apk, Bpk, diag, n);

    // 32 rowblocks x 16 splits, XCD-decoded in-kernel, 2 blocks/CU
    gemm_lse_kernel<<<(n / 256) * 16, 256, 0, stream>>>(Apk, Bpk, partial, n);

    const int nred = (n + 255) / 256;  // 32
    row_lse_kernel<<<nred, 256, 0, stream>>>(partial, diag, bsum, n);
    final_kernel<<<1, 64, 0, stream>>>(bsum, out, nred, n);
}

// Round 15
// 89.589 us; speedup vs baseline: 1.2935x; 1.0086x over previous
//
#include <hip/hip_runtime.h>
#include <hip/hip_bf16.h>
#include <math.h>

#define DIM 256

typedef float f32x4 __attribute__((ext_vector_type(4)));
typedef int   i32x8 __attribute__((ext_vector_type(8)));

__constant__ const float kTempInvLog2e = 20.0f * 1.4426950408889634f; // (1/temp)*log2(e)
#define LN2 0.6931471805599453f
#define EPS_NORM 1e-8f
#define SCALE_ONE 0x7F7F7F7Fu   // e8m0 bias-127 in every byte = x1.0

// f32x4 -> 4 packed OCP e4m3 bytes via HW cvt_pk (2 instrs, RNE-sat)
static __device__ inline unsigned f2fp8x4(float4 v, float s) {
    int r = 0;
    r = __builtin_amdgcn_cvt_pk_fp8_f32(v.x * s, v.y * s, r, false); // low word
    r = __builtin_amdgcn_cvt_pk_fp8_f32(v.z * s, v.w * s, r, true);  // high word
    return (unsigned)r;
}

// assemble a 32-byte (8 VGPR) MFMA operand from two 16-B pieces
static __device__ inline i32x8 ld_frag32(const void* p0, const void* p1) {
    uint4 a = *(const uint4*)p0;
    uint4 b = *(const uint4*)p1;
    i32x8 v;
    v[0] = a.x; v[1] = a.y; v[2] = a.z; v[3] = a.w;
    v[4] = b.x; v[5] = b.y; v[6] = b.z; v[7] = b.w;
    return v;
}

// Kernel 1: normalize + fp8-quantize (HW cvt) + PACK for the K=128 scaled-MFMA
// fragment. Also zeroes rowsum[] (ws is 0xAA-poisoned each run) and writes
// diag[r] (exact fp32). Layout: 16-row tile T, K-chunk kc (128 k each);
// chunk CI = T*2+kc is 2048 B: byte = CI*2048 + piece*1024 + lane*16,
// lane = rowlocal + 16*g, holding X[row][kc*128 + g*32 + piece*16 .. +16].
__global__ __launch_bounds__(256) void normpack_kernel(
    const float* __restrict__ A, const float* __restrict__ B,
    unsigned char* __restrict__ Apk, unsigned char* __restrict__ Bpk,
    float* __restrict__ diag, float* __restrict__ rowsum, int n)
{
    __shared__ uint4 lA[256];
    __shared__ uint4 lB[256];
    const int t = threadIdx.x;
    const int rl = t >> 4;       // row-local 0..15
    const int c16 = t & 15;      // 16-elem chunk: abs k in [16*c16, 16*c16+16)
    const int r = blockIdx.x * 16 + rl;

    const float4* pa = (const float4*)(A + (size_t)r * DIM + c16 * 16);
    const float4* pb = (const float4*)(B + (size_t)r * DIM + c16 * 16);
    float4 a0 = pa[0], a1 = pa[1], a2 = pa[2], a3 = pa[3];
    float4 b0 = pb[0], b1 = pb[1], b2 = pb[2], b3 = pb[3];

    float ssa = a0.x*a0.x + a0.y*a0.y + a0.z*a0.z + a0.w*a0.w
              + a1.x*a1.x + a1.y*a1.y + a1.z*a1.z + a1.w*a1.w
              + a2.x*a2.x + a2.y*a2.y + a2.z*a2.z + a2.w*a2.w
              + a3.x*a3.x + a3.y*a3.y + a3.z*a3.z + a3.w*a3.w;
    float ssb = b0.x*b0.x + b0.y*b0.y + b0.z*b0.z + b0.w*b0.w
              + b1.x*b1.x + b1.y*b1.y + b1.z*b1.z + b1.w*b1.w
              + b2.x*b2.x + b2.y*b2.y + b2.z*b2.z + b2.w*b2.w
              + b3.x*b3.x + b3.y*b3.y + b3.z*b3.z + b3.w*b3.w;
    float dd  = a0.x*b0.x + a0.y*b0.y + a0.z*b0.z + a0.w*b0.w
              + a1.x*b1.x + a1.y*b1.y + a1.z*b1.z + a1.w*b1.w
              + a2.x*b2.x + a2.y*b2.y + a2.z*b2.z + a2.w*b2.w
              + a3.x*b3.x + a3.y*b3.y + a3.z*b3.z + a3.w*b3.w;
#pragma unroll
    for (int m = 1; m < 16; m <<= 1) {
        ssa += __shfl_xor(ssa, m, 64);
        ssb += __shfl_xor(ssb, m, 64);
        dd  += __shfl_xor(dd, m, 64);
    }
    float na = fmaxf(sqrtf(ssa), EPS_NORM);
    float nb = fmaxf(sqrtf(ssb), EPS_NORM);
    float sa = kTempInvLog2e / na;
    float sb = 1.0f / nb;
    if (c16 == 0) {
        diag[r] = dd / (na * nb) * kTempInvLog2e;
        rowsum[r] = 0.0f;   // init for gemm's atomicAdd (ws is poisoned)
    }

    // kc = c16>>3, g = (c16&7)>>1, piece = c16&1, lane = rl + 16*g
    const int u = ((c16 >> 3) << 7) + ((c16 & 1) << 6) + rl + ((c16 & 7) >> 1) * 16;
    uint4 ga, gb;
    ga.x = f2fp8x4(a0, sa); ga.y = f2fp8x4(a1, sa);
    ga.z = f2fp8x4(a2, sa); ga.w = f2fp8x4(a3, sa);
    gb.x = f2fp8x4(b0, sb); gb.y = f2fp8x4(b1, sb);
    gb.z = f2fp8x4(b2, sb); gb.w = f2fp8x4(b3, sb);
    lA[u] = ga; lB[u] = gb;
    __syncthreads();

    ((uint4*)Apk)[(size_t)blockIdx.x * 256 + t] = lA[t];
    ((uint4*)Bpk)[(size_t)blockIdx.x * 256 + t] = lB[t];
}

// async 16B/lane global->LDS copy (wave-uniform LDS base + lane*16)
static __device__ inline void async_copy16(const void* g, void* l) {
    __builtin_amdgcn_global_load_lds(
        (const __attribute__((address_space(1))) unsigned int*)g,
        (__attribute__((address_space(3))) unsigned int*)l, 16, 0, 0);
}

// Kernel 2 (R9/R14 config — measured optimum) + atomic row-sum epilogue:
// fused MX-fp8 GEMM (16x16x128, identity scales) + exp2 + per-row sums
// reduced across splits via device-scope atomicAdd (16 writers/row).
// Block = 256 thr (4 waves). Block tile = 256 rows x 512 cols (1 of 16 splits).
// Wave w owns 64 rows: afrag[4 m][2 kc] i32x8 pinned. B streamed as 32-col
// tiles (8 KB packed) through a 2x8 KB LDS double buffer via global_load_lds.
// Grid = 32 rowblocks x 16 splits = 512 blocks (2/CU). XCD-pinned splits.
__global__ __launch_bounds__(256, 2) void gemm_lse_kernel(
    const unsigned char* __restrict__ Apk, const unsigned char* __restrict__ Bpk,
    float* __restrict__ rowsum, int n)
{
    __shared__ char ldsbuf[16384];   // 2 x 8 KB B-tile double buffer
    const int lane = threadIdx.x & 63;
    const int w = threadIdx.x >> 6;
    const int c = lane & 15;
    const int q = lane >> 4;

    const int i = blockIdx.x;
    const int split = ((i & 7) << 1) | ((i >> 3) & 1);  // 0..15, XCD-pinned
    const int rowblk = i >> 4;                           // 0..31
    const int rowbase = rowblk * 256 + w * 64;

    // A fragments: 4 row-tiles x 2 K-chunks, 32 B/lane each (two 16-B pieces)
    i32x8 afrag[4][2];
#pragma unroll
    for (int m = 0; m < 4; ++m) {
        const int AT = rowblk * 16 + w * 4 + m;
#pragma unroll
        for (int kc = 0; kc < 2; ++kc) {
            const char* base = (const char*)Apk + ((size_t)AT * 2 + kc) * 2048 + lane * 16;
            afrag[m][kc] = ld_frag32(base, base + 1024);
        }
    }
#pragma unroll
    for (int m = 0; m < 4; ++m)
#pragma unroll
        for (int kc = 0; kc < 2; ++kc)
            asm volatile("" : "+v"(afrag[m][kc]));  // keep resident

    float sums[16];
#pragma unroll
    for (int s = 0; s < 16; ++s) sums[s] = 0.0f;

    const char* bbase = (const char*)Bpk + (size_t)split * 32 * 4096; // 128 KB slice
    const int niter = 16;   // 16 iters of 32 cols

    // stage tile 0 into buffer 0 (each wave copies its 2 KB quarter)
    {
        const char* src = bbase + w * 2048 + (size_t)lane * 16;
        char* dst = ldsbuf + w * 2048;
        async_copy16(src, dst);
        async_copy16(src + 1024, dst + 1024);
    }
    __syncthreads();

    for (int it = 0; it < niter; ++it) {
        const int cur = it & 1;
        if (it + 1 < niter) {   // async prefetch next 8 KB tile
            const char* src = bbase + (size_t)(it + 1) * 8192 + w * 2048 + (size_t)lane * 16;
            char* dst = ldsbuf + (cur ^ 1) * 8192 + w * 2048;
            async_copy16(src, dst);
            async_copy16(src + 1024, dst + 1024);
        }

        f32x4 acc[4][2];
#pragma unroll
        for (int m = 0; m < 4; ++m)
#pragma unroll
            for (int nc = 0; nc < 2; ++nc)
                acc[m][nc] = (f32x4){0.f, 0.f, 0.f, 0.f};

        const char* lb = ldsbuf + cur * 8192 + (size_t)lane * 16;
#pragma unroll
        for (int nc = 0; nc < 2; ++nc) {
#pragma unroll
            for (int kc = 0; kc < 2; ++kc) {
                const char* p = lb + nc * 4096 + kc * 2048;
                i32x8 bfrag = ld_frag32(p, p + 1024);
#pragma unroll
                for (int m = 0; m < 4; ++m)
                    acc[m][nc] = __builtin_amdgcn_mfma_scale_f32_16x16x128_f8f6f4(
                        afrag[m][kc], bfrag, acc[m][nc],
                        0, 0,                       // cbsz=fp8(e4m3), blgp=fp8(e4m3)
                        0, SCALE_ONE,               // opsel_a, scale_a (x1.0)
                        0, SCALE_ONE);              // opsel_b, scale_b (x1.0)
            }
        }

#pragma unroll
        for (int m = 0; m < 4; ++m)
#pragma unroll
            for (int nc = 0; nc < 2; ++nc)
#pragma unroll
                for (int r = 0; r < 4; ++r)
                    sums[m * 4 + r] += __builtin_amdgcn_exp2f(acc[m][nc][r]);

        __syncthreads();   // staging of it+1 complete; all waves done with cur
    }

    // reduce row sums across the 16 lanes of each q-group (cols mod 16)
#pragma unroll
    for (int s = 0; s < 16; ++s) {
        float v = sums[s];
        v += __shfl_xor(v, 1, 64);
        v += __shfl_xor(v, 2, 64);
        v += __shfl_xor(v, 4, 64);
        v += __shfl_xor(v, 8, 64);
        sums[s] = v;
    }
    if (c == 0) {
#pragma unroll
        for (int m = 0; m < 4; ++m)
#pragma unroll
            for (int r = 0; r < 4; ++r)
                atomicAdd(&rowsum[rowbase + m * 16 + q * 4 + r], sums[m * 4 + r]);
    }
}

// Kernel 3: single-block finale over SMALL data (64 KB: rowsum + diag).
// loss = (ln2/n) * sum_rows( log2(rowsum[row]) - diag[row] )
__global__ __launch_bounds__(1024) void finale_kernel(
    const float* __restrict__ rowsum, const float* __restrict__ diag,
    float* __restrict__ out, int n)
{
    __shared__ float red[1024];
    float local = 0.0f;
    for (int row = threadIdx.x; row < n; row += 1024)
        local += log2f(rowsum[row]) - diag[row];
    red[threadIdx.x] = local;
    __syncthreads();
    for (int off = 512; off > 0; off >>= 1) {
        if (threadIdx.x < off) red[threadIdx.x] += red[threadIdx.x + off];
        __syncthreads();
    }
    if (threadIdx.x == 0) out[0] = red[0] * (LN2 / (float)n);
}

extern "C" void kernel_launch(void* const* d_in, const int* in_sizes, int n_in,
                              void* d_out, int out_size, void* d_ws, size_t ws_size,
                              hipStream_t stream) {
    const int n = in_sizes[0] / DIM;  // 8192
    const float* A = (const float*)d_in[0];
    const float* B = (const float*)d_in[1];
    float* out = (float*)d_out;

    // workspace layout
    unsigned char* Apk = (unsigned char*)d_ws;                   // n*DIM fp8 (2 MB)
    unsigned char* Bpk = Apk + (size_t)n * DIM;                  // n*DIM fp8 (2 MB)
    float* rowsum = (float*)(Bpk + (size_t)n * DIM);             // n f32
    float* diag = rowsum + n;                                    // n f32

    normpack_kernel<<<n / 16, 256, 0, stream>>>(A, B, Apk, Bpk, diag, rowsum, n);

    // 32 rowblocks x 16 splits, XCD-decoded in-kernel, 2 blocks/CU
    gemm_lse_kernel<<<(n / 256) * 16, 256, 0, stream>>>(Apk, Bpk, rowsum, n);

    finale_kernel<<<1, 1024, 0, stream>>>(rowsum, diag, out, n);
}